// Round 1
// baseline (271.915 us; speedup 1.0000x reference)
//
#include <hip/hip_runtime.h>
#include <stdint.h>

typedef unsigned short u16;
typedef float  f32x4  __attribute__((ext_vector_type(4)));
typedef __bf16 bf16x8 __attribute__((ext_vector_type(8)));
typedef unsigned short u16x8 __attribute__((ext_vector_type(8)));
typedef unsigned short u16x4v __attribute__((ext_vector_type(4)));

#define S_LEN 2048
#define E_DIM 2048
#define HD    128
#define QH    16
#define KVH   4
#define KVD   512
#define NQKV  3072
#define QK_SCALE 0.08838834764831845f  // 1/sqrt(128)

__device__ __forceinline__ u16 f2bf(float f) {
  union { float f; uint32_t u; } v; v.f = f;
  return (u16)((v.u + 0x7FFFu + ((v.u >> 16) & 1u)) >> 16);
}

// ---------------- cast fp32 -> bf16, 4 elems/thread ----------------
__global__ void cast_bf16_kernel(const float* __restrict__ in, u16* __restrict__ out) {
  int i = blockIdx.x * blockDim.x + threadIdx.x;
  float4 f = reinterpret_cast<const float4*>(in)[i];
  u16x4v o;
  o[0] = f2bf(f.x); o[1] = f2bf(f.y); o[2] = f2bf(f.z); o[3] = f2bf(f.w);
  reinterpret_cast<u16x4v*>(out)[i] = o;
}

// ---------------- GEMM: C[M,N] = A[M,K] * B[N,K]^T (+bias), bf16 in, fp32 out
// 128x128 tile, BK=64, 256 threads (4 waves as 2x2 of 64x64)
template<bool BIAS>
__global__ __launch_bounds__(256) void gemm_bt_kernel(
    const u16* __restrict__ A, const u16* __restrict__ B,
    float* __restrict__ C, const float* __restrict__ bias,
    int M, int N, int K)
{
  __shared__ u16 As[128 * 64];
  __shared__ u16 Bs[128 * 64];

  const int tid  = threadIdx.x;
  const int lane = tid & 63;
  const int wid  = tid >> 6;
  const int wr   = (wid >> 1) * 64;
  const int wc   = (wid & 1) * 64;
  const int lr   = lane & 15;
  const int kg   = lane >> 4;

  const int bm = blockIdx.y * 128;
  const int bn = blockIdx.x * 128;

  f32x4 acc[4][4];
  #pragma unroll
  for (int r = 0; r < 4; ++r)
    #pragma unroll
    for (int c = 0; c < 4; ++c) acc[r][c] = (f32x4){0.f, 0.f, 0.f, 0.f};

  const int srow = tid >> 3;  // 0..31, +i*32 covers 128 rows
  const int sch  = tid & 7;   // 16B chunk within 64-elem row

  for (int kt = 0; kt < K; kt += 64) {
    u16x8 av[4], bv[4];
    #pragma unroll
    for (int i = 0; i < 4; ++i) {
      av[i] = *reinterpret_cast<const u16x8*>(A + (size_t)(bm + srow + i*32)*K + kt + sch*8);
      bv[i] = *reinterpret_cast<const u16x8*>(B + (size_t)(bn + srow + i*32)*K + kt + sch*8);
    }
    __syncthreads();  // prior tile's reads done
    #pragma unroll
    for (int i = 0; i < 4; ++i) {
      *reinterpret_cast<u16x8*>(&As[(srow + i*32)*64 + sch*8]) = av[i];
      *reinterpret_cast<u16x8*>(&Bs[(srow + i*32)*64 + sch*8]) = bv[i];
    }
    __syncthreads();
    #pragma unroll
    for (int kk = 0; kk < 2; ++kk) {
      bf16x8 af[4], bfr[4];
      #pragma unroll
      for (int r = 0; r < 4; ++r)
        af[r] = *reinterpret_cast<const bf16x8*>(&As[(wr + r*16 + lr)*64 + kk*32 + kg*8]);
      #pragma unroll
      for (int c = 0; c < 4; ++c)
        bfr[c] = *reinterpret_cast<const bf16x8*>(&Bs[(wc + c*16 + lr)*64 + kk*32 + kg*8]);
      #pragma unroll
      for (int r = 0; r < 4; ++r)
        #pragma unroll
        for (int c = 0; c < 4; ++c)
          acc[r][c] = __builtin_amdgcn_mfma_f32_16x16x32_bf16(af[r], bfr[c], acc[r][c], 0, 0, 0);
    }
  }

  const int crow = kg * 4;
  #pragma unroll
  for (int r = 0; r < 4; ++r) {
    #pragma unroll
    for (int c = 0; c < 4; ++c) {
      int gr = bm + wr + r*16 + crow;
      int gc = bn + wc + c*16 + lr;
      float badd = BIAS ? bias[gc] : 0.0f;
      #pragma unroll
      for (int reg = 0; reg < 4; ++reg)
        C[(size_t)(gr + reg)*N + gc] = acc[r][c][reg] + badd;
    }
  }
}

// ---------------- RoPE + split qkv_f32 -> q_bf16 (scaled), k_bf16 ----------------
__global__ void rope_split_kernel(const float* __restrict__ qkv,
                                  u16* __restrict__ qb, u16* __restrict__ kb) {
  int idx = blockIdx.x * blockDim.x + threadIdx.x;  // 0 .. 2048*1280
  int s  = idx / 1280;
  int cp = idx - s * 1280;
  int col = cp * 2;  // 0..2558 (q: 0..2047, k: 2048..2559)
  const float* src = qkv + (size_t)s * NQKV + col;
  float x0 = src[0], x1 = src[1];
  int p = (col & 127) >> 1;  // pair index within head (0..63)
  float inv = exp2f((float)p * (-13.287712379549449f / 64.0f));  // 10000^(-p/64)
  float ang = (float)s * inv;
  float sn, cs;
  sincosf(ang, &sn, &cs);
  float o0 = x0 * cs - x1 * sn;
  float o1 = x0 * sn + x1 * cs;
  if (col < E_DIM) {
    o0 *= QK_SCALE; o1 *= QK_SCALE;
    qb[(size_t)s * E_DIM + col]     = f2bf(o0);
    qb[(size_t)s * E_DIM + col + 1] = f2bf(o1);
  } else {
    kb[(size_t)s * KVD + (col - E_DIM)]     = f2bf(o0);
    kb[(size_t)s * KVD + (col - E_DIM) + 1] = f2bf(o1);
  }
}

// ---------------- V transpose: qkv_f32 v-block (S x 512) -> vT bf16 (512 x S) ----
__global__ void transpose_v_kernel(const float* __restrict__ qkv, u16* __restrict__ vT) {
  __shared__ float tile[32][33];
  const int sbase = blockIdx.x * 32;
  const int cbase = blockIdx.y * 32;
  const int tx = threadIdx.x;
  const int ty = threadIdx.y;
  #pragma unroll
  for (int i = 0; i < 32; i += 8)
    tile[ty + i][tx] = qkv[(size_t)(sbase + ty + i) * NQKV + (E_DIM + KVD) + cbase + tx];
  __syncthreads();
  #pragma unroll
  for (int i = 0; i < 32; i += 8)
    vT[(size_t)(cbase + ty + i) * S_LEN + sbase + tx] = f2bf(tile[tx][ty + i]);
}

// ---------------- Flash attention (causal, GQA 4:1), bf16 in/out ----------------
// grid (S/64, 16 heads), 256 threads. Wave w owns q rows [qt*64+w*16, +16).
__global__ __launch_bounds__(256) void attn_kernel(
    const u16* __restrict__ Q, const u16* __restrict__ Kc,
    const u16* __restrict__ VT, u16* __restrict__ Out)
{
  __shared__ u16 Ks[64 * 128];   // [kv][d]
  __shared__ u16 VTs[128 * 64];  // [d][kv]
  __shared__ u16 Ps[4][16][72];  // per-wave P staging, padded rows (144B, 16B-aligned)

  const int qt  = blockIdx.x;
  const int h   = blockIdx.y;
  const int kvh = h >> 2;
  const int tid  = threadIdx.x;
  const int lane = tid & 63;
  const int wid  = tid >> 6;
  const int lr   = lane & 15;
  const int kg   = lane >> 4;

  const int qrow0 = qt * 64 + wid * 16;

  bf16x8 qf[4];
  {
    const u16* qbase = Q + (size_t)(qrow0 + lr) * E_DIM + h * HD + kg * 8;
    #pragma unroll
    for (int kk = 0; kk < 4; ++kk)
      qf[kk] = *reinterpret_cast<const bf16x8*>(qbase + kk * 32);
  }

  f32x4 o[8];
  #pragma unroll
  for (int d = 0; d < 8; ++d) o[d] = (f32x4){0.f, 0.f, 0.f, 0.f};
  float mr[4], lsum[4];
  #pragma unroll
  for (int r = 0; r < 4; ++r) { mr[r] = -1e30f; lsum[r] = 0.f; }

  for (int t = 0; t <= qt; ++t) {
    u16x8 kreg[4], vreg[4];
    #pragma unroll
    for (int i = 0; i < 4; ++i) {
      int c = i * 256 + tid;
      kreg[i] = *reinterpret_cast<const u16x8*>(
          Kc + (size_t)(t*64 + (c >> 4)) * KVD + kvh * HD + (c & 15) * 8);
      vreg[i] = *reinterpret_cast<const u16x8*>(
          VT + (size_t)(kvh * HD + (c >> 3)) * S_LEN + t*64 + (c & 7) * 8);
    }
    __syncthreads();  // prior tile compute done before overwrite
    #pragma unroll
    for (int i = 0; i < 4; ++i) {
      int c = i * 256 + tid;
      *reinterpret_cast<u16x8*>(&Ks[c * 8])  = kreg[i];
      *reinterpret_cast<u16x8*>(&VTs[c * 8]) = vreg[i];
    }
    __syncthreads();

    // S = Q * K^T  (scale pre-folded into Q)
    f32x4 sacc[4];
    #pragma unroll
    for (int c = 0; c < 4; ++c) sacc[c] = (f32x4){0.f, 0.f, 0.f, 0.f};
    #pragma unroll
    for (int kk = 0; kk < 4; ++kk) {
      #pragma unroll
      for (int c = 0; c < 4; ++c) {
        bf16x8 bfr = *reinterpret_cast<const bf16x8*>(&Ks[(c*16 + lr)*128 + kk*32 + kg*8]);
        sacc[c] = __builtin_amdgcn_mfma_f32_16x16x32_bf16(qf[kk], bfr, sacc[c], 0, 0, 0);
      }
    }
    if (t == qt) {  // causal mask on the diagonal tile
      #pragma unroll
      for (int c = 0; c < 4; ++c) {
        int col = t*64 + c*16 + lr;
        #pragma unroll
        for (int reg = 0; reg < 4; ++reg) {
          int row = qrow0 + kg*4 + reg;
          if (col > row) sacc[c][reg] = -1e30f;
        }
      }
    }
    // online softmax (rows live across 16 lanes; reduce via shfl_xor 1,2,4,8)
    float p[4][4];
    #pragma unroll
    for (int reg = 0; reg < 4; ++reg) {
      float mx = fmaxf(fmaxf(sacc[0][reg], sacc[1][reg]), fmaxf(sacc[2][reg], sacc[3][reg]));
      mx = fmaxf(mx, __shfl_xor(mx, 1));
      mx = fmaxf(mx, __shfl_xor(mx, 2));
      mx = fmaxf(mx, __shfl_xor(mx, 4));
      mx = fmaxf(mx, __shfl_xor(mx, 8));
      float nm = fmaxf(mr[reg], mx);
      float sum = 0.f;
      #pragma unroll
      for (int c = 0; c < 4; ++c) {
        p[c][reg] = __expf(sacc[c][reg] - nm);
        sum += p[c][reg];
      }
      sum += __shfl_xor(sum, 1);
      sum += __shfl_xor(sum, 2);
      sum += __shfl_xor(sum, 4);
      sum += __shfl_xor(sum, 8);
      float alpha = __expf(mr[reg] - nm);
      lsum[reg] = lsum[reg] * alpha + sum;
      mr[reg] = nm;
      #pragma unroll
      for (int d = 0; d < 8; ++d) o[d][reg] *= alpha;
    }
    // P: D-layout -> A-layout via per-wave LDS (same-wave RAW; compiler orders)
    #pragma unroll
    for (int c = 0; c < 4; ++c)
      #pragma unroll
      for (int reg = 0; reg < 4; ++reg)
        Ps[wid][kg*4 + reg][c*16 + lr] = f2bf(p[c][reg]);
    // O += P * V
    #pragma unroll
    for (int kk = 0; kk < 2; ++kk) {
      bf16x8 pa = *reinterpret_cast<const bf16x8*>(&Ps[wid][lr][kk*32 + kg*8]);
      #pragma unroll
      for (int d = 0; d < 8; ++d) {
        bf16x8 vb = *reinterpret_cast<const bf16x8*>(&VTs[(d*16 + lr)*64 + kk*32 + kg*8]);
        o[d] = __builtin_amdgcn_mfma_f32_16x16x32_bf16(pa, vb, o[d], 0, 0, 0);
      }
    }
  }

  #pragma unroll
  for (int reg = 0; reg < 4; ++reg) {
    float inv = 1.0f / lsum[reg];
    int grow = qrow0 + kg*4 + reg;
    #pragma unroll
    for (int d = 0; d < 8; ++d)
      Out[(size_t)grow * E_DIM + h * HD + d*16 + lr] = f2bf(o[d][reg] * inv);
  }
}

// ---------------- launch ----------------
extern "C" void kernel_launch(void* const* d_in, const int* in_sizes, int n_in,
                              void* d_out, int out_size, void* d_ws, size_t ws_size,
                              hipStream_t stream)
{
  const float* x  = (const float*)d_in[0];
  const float* Wq = (const float*)d_in[1];
  const float* Wk = (const float*)d_in[2];
  const float* Wv = (const float*)d_in[3];
  const float* Wo = (const float*)d_in[4];
  const float* bo = (const float*)d_in[5];
  float* out = (float*)d_out;

  char* w = (char*)d_ws;
  u16*   xb   = (u16*)(w);                   // 8 MB  x bf16 (2048x2048)
  u16*   Wcat = (u16*)(w + (8u  << 20));     // 12 MB [Wq;Wk;Wv] bf16 (3072x2048)
  u16*   Wob  = (u16*)(w + (20u << 20));     // 8 MB  Wo bf16
  float* qkv  = (float*)(w + (28u << 20));   // 24 MB qkv fp32 (2048x3072)
  u16*   qb   = (u16*)(w + (52u << 20));     // 8 MB  q bf16 roped+scaled
  u16*   kb   = (u16*)(w + (60u << 20));     // 2 MB  k bf16 roped
  u16*   vT   = (u16*)(w + (62u << 20));     // 2 MB  v^T bf16 (512x2048)
  u16*   attn = (u16*)(w + (64u << 20));     // 8 MB  attention out bf16
  (void)ws_size; (void)in_sizes; (void)n_in; (void)out_size;

  cast_bf16_kernel<<<4096, 256, 0, stream>>>(x,  xb);
  cast_bf16_kernel<<<4096, 256, 0, stream>>>(Wq, Wcat);
  cast_bf16_kernel<<<1024, 256, 0, stream>>>(Wk, Wcat + (size_t)E_DIM * E_DIM);
  cast_bf16_kernel<<<1024, 256, 0, stream>>>(Wv, Wcat + (size_t)(E_DIM + KVD) * E_DIM);
  cast_bf16_kernel<<<4096, 256, 0, stream>>>(Wo, Wob);

  gemm_bt_kernel<false><<<dim3(NQKV/128, S_LEN/128), 256, 0, stream>>>(
      xb, Wcat, qkv, nullptr, S_LEN, NQKV, E_DIM);

  rope_split_kernel<<<(S_LEN * 1280) / 256, 256, 0, stream>>>(qkv, qb, kb);
  transpose_v_kernel<<<dim3(S_LEN/32, KVD/32), dim3(32, 8), 0, stream>>>(qkv, vT);

  attn_kernel<<<dim3(S_LEN/64, QH), 256, 0, stream>>>(qb, kb, vT, attn);

  gemm_bt_kernel<true><<<dim3(E_DIM/128, S_LEN/128), 256, 0, stream>>>(
      attn, Wob, out, bo, S_LEN, E_DIM, E_DIM);
}

// Round 2
// 189.759 us; speedup vs baseline: 1.4330x; 1.4330x over previous
//
#include <hip/hip_runtime.h>
#include <stdint.h>

typedef unsigned short u16;
typedef float  f32x4  __attribute__((ext_vector_type(4)));
typedef __bf16 bf16x8 __attribute__((ext_vector_type(8)));
typedef unsigned short u16x8 __attribute__((ext_vector_type(8)));
typedef unsigned short u16x4v __attribute__((ext_vector_type(4)));

#define S_LEN 2048
#define E_DIM 2048
#define HD    128
#define QH    16
#define KVH   4
#define KVD   512
#define NQKV  3072
#define QK_SCALE 0.08838834764831845f  // 1/sqrt(128)

__device__ __forceinline__ u16 f2bf(float f) {
  union { float f; uint32_t u; } v; v.f = f;
  return (u16)((v.u + 0x7FFFu + ((v.u >> 16) & 1u)) >> 16);
}

// ---------------- cast fp32 -> bf16, 4 elems/thread ----------------
__global__ void cast_bf16_kernel(const float* __restrict__ in, u16* __restrict__ out) {
  int i = blockIdx.x * blockDim.x + threadIdx.x;
  float4 f = reinterpret_cast<const float4*>(in)[i];
  u16x4v o;
  o[0] = f2bf(f.x); o[1] = f2bf(f.y); o[2] = f2bf(f.z); o[3] = f2bf(f.w);
  reinterpret_cast<u16x4v*>(out)[i] = o;
}

// ---------------- GEMM: C[M,N] = A[M,K] * B[N,K]^T (+bias), bf16 in, fp32 out
// 128x128 tile, BK=64, 256 threads (4 waves as 2x2 of 64x64).
// Staging: global_load_lds width-16, linear LDS dest, source-side XOR swizzle
// (chunk ^= row&7); frag reads apply the same XOR -> conflict-free b128.
template<bool BIAS>
__global__ __launch_bounds__(256) void gemm_bt_kernel(
    const u16* __restrict__ A, const u16* __restrict__ B,
    float* __restrict__ C, const float* __restrict__ bias,
    int M, int N, int K)
{
  __shared__ u16 As[128 * 64];
  __shared__ u16 Bs[128 * 64];

  const int tid  = threadIdx.x;
  const int lane = tid & 63;
  const int wid  = tid >> 6;
  const int wr   = (wid >> 1) * 64;
  const int wc   = (wid & 1) * 64;
  const int lr   = lane & 15;
  const int kg   = lane >> 4;

  const int bm = blockIdx.y * 128;
  const int bn = blockIdx.x * 128;

  f32x4 acc[4][4];
  #pragma unroll
  for (int r = 0; r < 4; ++r)
    #pragma unroll
    for (int c = 0; c < 4; ++c) acc[r][c] = (f32x4){0.f, 0.f, 0.f, 0.f};

  // staging geometry: wave w covers rows [w*32, w*32+32); lane l covers
  // row w*32 + i*8 + (l>>3), LDS slot (l&7); source chunk = slot ^ (row&7).
  const int l8 = lane & 7;
  const int l3 = lane >> 3;
  const int schunk = l8 ^ l3;  // swizzled source chunk (16B units)

  const u16* gA = A + (size_t)(bm + wid*32 + l3) * K + schunk * 8;
  const u16* gB = B + (size_t)(bn + wid*32 + l3) * K + schunk * 8;
  u16* ldsA = &As[(wid * 32) * 64];
  u16* ldsB = &Bs[(wid * 32) * 64];

  const int sw = lr & 7;

  for (int kt = 0; kt < K; kt += 64) {
    __syncthreads();  // prior tile's ds_reads done before DMA overwrites
    #pragma unroll
    for (int i = 0; i < 4; ++i) {
      __builtin_amdgcn_global_load_lds(
          (const __attribute__((address_space(1))) void*)(gA + (size_t)i * 8 * K + kt),
          (__attribute__((address_space(3))) void*)(ldsA + i * 8 * 64), 16, 0, 0);
      __builtin_amdgcn_global_load_lds(
          (const __attribute__((address_space(1))) void*)(gB + (size_t)i * 8 * K + kt),
          (__attribute__((address_space(3))) void*)(ldsB + i * 8 * 64), 16, 0, 0);
    }
    __syncthreads();  // drains vmcnt -> LDS tile visible
    #pragma unroll
    for (int kk = 0; kk < 2; ++kk) {
      bf16x8 af[4], bfr[4];
      #pragma unroll
      for (int r = 0; r < 4; ++r)
        af[r] = *reinterpret_cast<const bf16x8*>(
            &As[(wr + r*16 + lr)*64 + ((kk*4 + kg) ^ sw)*8]);
      #pragma unroll
      for (int c = 0; c < 4; ++c)
        bfr[c] = *reinterpret_cast<const bf16x8*>(
            &Bs[(wc + c*16 + lr)*64 + ((kk*4 + kg) ^ sw)*8]);
      #pragma unroll
      for (int r = 0; r < 4; ++r)
        #pragma unroll
        for (int c = 0; c < 4; ++c)
          acc[r][c] = __builtin_amdgcn_mfma_f32_16x16x32_bf16(af[r], bfr[c], acc[r][c], 0, 0, 0);
    }
  }

  const int crow = kg * 4;
  #pragma unroll
  for (int r = 0; r < 4; ++r) {
    #pragma unroll
    for (int c = 0; c < 4; ++c) {
      int gr = bm + wr + r*16 + crow;
      int gc = bn + wc + c*16 + lr;
      float badd = BIAS ? bias[gc] : 0.0f;
      #pragma unroll
      for (int reg = 0; reg < 4; ++reg)
        C[(size_t)(gr + reg)*N + gc] = acc[r][c][reg] + badd;
    }
  }
}

// ---------------- RoPE + split qkv_f32 -> q_bf16 (scaled), k_bf16 ----------------
__global__ void rope_split_kernel(const float* __restrict__ qkv,
                                  u16* __restrict__ qb, u16* __restrict__ kb) {
  int idx = blockIdx.x * blockDim.x + threadIdx.x;  // 0 .. 2048*1280
  int s  = idx / 1280;
  int cp = idx - s * 1280;
  int col = cp * 2;  // q: 0..2047, k: 2048..2559
  const float* src = qkv + (size_t)s * NQKV + col;
  float x0 = src[0], x1 = src[1];
  int p = (col & 127) >> 1;  // pair index within head (0..63)
  float inv = exp2f((float)p * (-13.287712379549449f / 64.0f));  // 10000^(-p/64)
  float ang = (float)s * inv;
  float sn, cs;
  sincosf(ang, &sn, &cs);
  float o0 = x0 * cs - x1 * sn;
  float o1 = x0 * sn + x1 * cs;
  if (col < E_DIM) {
    o0 *= QK_SCALE; o1 *= QK_SCALE;
    qb[(size_t)s * E_DIM + col]     = f2bf(o0);
    qb[(size_t)s * E_DIM + col + 1] = f2bf(o1);
  } else {
    kb[(size_t)s * KVD + (col - E_DIM)]     = f2bf(o0);
    kb[(size_t)s * KVD + (col - E_DIM) + 1] = f2bf(o1);
  }
}

// ---------------- V transpose: qkv_f32 v-block (S x 512) -> vT bf16 (512 x S) ----
__global__ void transpose_v_kernel(const float* __restrict__ qkv, u16* __restrict__ vT) {
  __shared__ float tile[32][33];
  const int sbase = blockIdx.x * 32;
  const int cbase = blockIdx.y * 32;
  const int tx = threadIdx.x;
  const int ty = threadIdx.y;
  #pragma unroll
  for (int i = 0; i < 32; i += 8)
    tile[ty + i][tx] = qkv[(size_t)(sbase + ty + i) * NQKV + (E_DIM + KVD) + cbase + tx];
  __syncthreads();
  #pragma unroll
  for (int i = 0; i < 32; i += 8)
    vT[(size_t)(cbase + ty + i) * S_LEN + sbase + tx] = f2bf(tile[tx][ty + i]);
}

// ---------------- Flash attention tile (per wave: 16 q rows vs 64 kv) ----------
__device__ __forceinline__ void attn_tile(
    int t, int qt, int wid, int lr, int kg,
    const bf16x8* qf, f32x4* o, float* mr, float* ls,
    const u16* ks, const u16* vts, u16* ps)
{
  const int sw = lr & 7;
  f32x4 sacc[4];
  #pragma unroll
  for (int c = 0; c < 4; ++c) sacc[c] = (f32x4){0.f, 0.f, 0.f, 0.f};
  #pragma unroll
  for (int kk = 0; kk < 4; ++kk) {
    #pragma unroll
    for (int c = 0; c < 4; ++c) {
      bf16x8 bfr = *reinterpret_cast<const bf16x8*>(
          &ks[(c*16 + lr)*128 + ((kk*4 + kg) ^ sw)*8]);
      sacc[c] = __builtin_amdgcn_mfma_f32_16x16x32_bf16(qf[kk], bfr, sacc[c], 0, 0, 0);
    }
  }
  if (t == qt) {  // causal mask, diagonal tile only
    #pragma unroll
    for (int c = 0; c < 4; ++c) {
      int rel = (c*16 + lr) - (wid*16 + kg*4);
      #pragma unroll
      for (int reg = 0; reg < 4; ++reg)
        if (rel > reg) sacc[c][reg] = -1e30f;
    }
  }
  float p[4][4];
  #pragma unroll
  for (int reg = 0; reg < 4; ++reg) {
    float mx = fmaxf(fmaxf(sacc[0][reg], sacc[1][reg]), fmaxf(sacc[2][reg], sacc[3][reg]));
    mx = fmaxf(mx, __shfl_xor(mx, 1));
    mx = fmaxf(mx, __shfl_xor(mx, 2));
    mx = fmaxf(mx, __shfl_xor(mx, 4));
    mx = fmaxf(mx, __shfl_xor(mx, 8));
    float nm = fmaxf(mr[reg], mx);
    float sum = 0.f;
    #pragma unroll
    for (int c = 0; c < 4; ++c) {
      p[c][reg] = __expf(sacc[c][reg] - nm);
      sum += p[c][reg];
    }
    sum += __shfl_xor(sum, 1);
    sum += __shfl_xor(sum, 2);
    sum += __shfl_xor(sum, 4);
    sum += __shfl_xor(sum, 8);
    float alpha = __expf(mr[reg] - nm);
    ls[reg] = ls[reg] * alpha + sum;
    mr[reg] = nm;
    #pragma unroll
    for (int d = 0; d < 8; ++d) o[d][reg] *= alpha;
  }
  #pragma unroll
  for (int c = 0; c < 4; ++c)
    #pragma unroll
    for (int reg = 0; reg < 4; ++reg)
      ps[(kg*4 + reg)*72 + c*16 + lr] = f2bf(p[c][reg]);
  #pragma unroll
  for (int kk = 0; kk < 2; ++kk) {
    bf16x8 pa = *reinterpret_cast<const bf16x8*>(&ps[lr*72 + kk*32 + kg*8]);
    #pragma unroll
    for (int d = 0; d < 8; ++d) {
      bf16x8 vb = *reinterpret_cast<const bf16x8*>(
          &vts[(d*16 + lr)*64 + ((kk*4 + kg) ^ sw)*8]);
      o[d] = __builtin_amdgcn_mfma_f32_16x16x32_bf16(pa, vb, o[d], 0, 0, 0);
    }
  }
}

// ---------------- Flash attention (causal, GQA 4:1), paired q-tiles ------------
// grid (16 pairs, 16 heads), 256 threads. Block handles q-tiles {pi, 31-pi}
// (33 kv-tile iterations each -> perfectly balanced, 256 blocks = 1/CU).
// K/V double-buffered in LDS (XOR-swizzled), async-stage split, 1 barrier/tile.
__global__ __launch_bounds__(256, 1) void attn_kernel(
    const u16* __restrict__ Q, const u16* __restrict__ Kc,
    const u16* __restrict__ VT, u16* __restrict__ Out)
{
  __shared__ u16 Ks[2][64 * 128];
  __shared__ u16 VTs[2][128 * 64];
  __shared__ u16 Ps[4][16 * 72];

  const int pi  = blockIdx.x;
  const int h   = blockIdx.y;
  const int kvh = h >> 2;
  const int tid  = threadIdx.x;
  const int lane = tid & 63;
  const int wid  = tid >> 6;
  const int lr   = lane & 15;
  const int kg   = lane >> 4;

  const int qtA = pi, qtB = 31 - pi;
  const int NT = qtB + 1;

  bf16x8 qfA[4], qfB[4];
  {
    const u16* qa = Q + (size_t)(qtA*64 + wid*16 + lr) * E_DIM + h * HD + kg * 8;
    const u16* qb = Q + (size_t)(qtB*64 + wid*16 + lr) * E_DIM + h * HD + kg * 8;
    #pragma unroll
    for (int kk = 0; kk < 4; ++kk) {
      qfA[kk] = *reinterpret_cast<const bf16x8*>(qa + kk * 32);
      qfB[kk] = *reinterpret_cast<const bf16x8*>(qb + kk * 32);
    }
  }

  f32x4 oA[8], oB[8];
  float mrA[4], lsA[4], mrB[4], lsB[4];
  #pragma unroll
  for (int d = 0; d < 8; ++d) { oA[d] = (f32x4){0.f,0.f,0.f,0.f}; oB[d] = (f32x4){0.f,0.f,0.f,0.f}; }
  #pragma unroll
  for (int r = 0; r < 4; ++r) { mrA[r] = -1e30f; lsA[r] = 0.f; mrB[r] = -1e30f; lsB[r] = 0.f; }

  u16x8 kreg[4], vreg[4];
  const u16* kbase = Kc + kvh * HD;
  const u16* vbase = VT + (size_t)(kvh * HD) * S_LEN;

  auto stage_load = [&](int t) {
    #pragma unroll
    for (int i = 0; i < 4; ++i) {
      int c = i * 256 + tid;
      kreg[i] = *reinterpret_cast<const u16x8*>(
          kbase + (size_t)(t*64 + (c >> 4)) * KVD + (c & 15) * 8);
      vreg[i] = *reinterpret_cast<const u16x8*>(
          vbase + (size_t)(c >> 3) * S_LEN + t*64 + (c & 7) * 8);
    }
  };
  auto stage_write = [&](int b) {
    #pragma unroll
    for (int i = 0; i < 4; ++i) {
      int c = i * 256 + tid;
      int kr = c >> 4, kc = c & 15;
      *reinterpret_cast<u16x8*>(&Ks[b][kr*128 + (kc ^ (kr & 7))*8]) = kreg[i];
      int vr = c >> 3, vc = c & 7;
      *reinterpret_cast<u16x8*>(&VTs[b][vr*64 + (vc ^ (vr & 7))*8]) = vreg[i];
    }
  };

  int p = 0;
  stage_load(0);
  stage_write(0);
  __syncthreads();

  for (int t = 0; t < NT; ++t) {
    if (t + 1 < NT) stage_load(t + 1);  // issue early: latency hides under compute
    attn_tile(t, qtB, wid, lr, kg, qfB, oB, mrB, lsB, Ks[p], VTs[p], Ps[wid]);
    if (t <= qtA)
      attn_tile(t, qtA, wid, lr, kg, qfA, oA, mrA, lsA, Ks[p], VTs[p], Ps[wid]);
    if (t + 1 < NT) {
      stage_write(p ^ 1);  // vmcnt wait lands here, after compute
      __syncthreads();     // single barrier per tile
      p ^= 1;
    }
  }

  #pragma unroll
  for (int reg = 0; reg < 4; ++reg) {
    float iA = 1.0f / lsA[reg];
    float iB = 1.0f / lsB[reg];
    int ga = qtA*64 + wid*16 + kg*4 + reg;
    int gb = qtB*64 + wid*16 + kg*4 + reg;
    #pragma unroll
    for (int d = 0; d < 8; ++d) {
      Out[(size_t)ga * E_DIM + h * HD + d*16 + lr] = f2bf(oA[d][reg] * iA);
      Out[(size_t)gb * E_DIM + h * HD + d*16 + lr] = f2bf(oB[d][reg] * iB);
    }
  }
}

// ---------------- launch ----------------
extern "C" void kernel_launch(void* const* d_in, const int* in_sizes, int n_in,
                              void* d_out, int out_size, void* d_ws, size_t ws_size,
                              hipStream_t stream)
{
  const float* x  = (const float*)d_in[0];
  const float* Wq = (const float*)d_in[1];
  const float* Wk = (const float*)d_in[2];
  const float* Wv = (const float*)d_in[3];
  const float* Wo = (const float*)d_in[4];
  const float* bo = (const float*)d_in[5];
  float* out = (float*)d_out;

  char* w = (char*)d_ws;
  u16*   xb   = (u16*)(w);                   // 8 MB  x bf16 (2048x2048)
  u16*   Wcat = (u16*)(w + (8u  << 20));     // 12 MB [Wq;Wk;Wv] bf16 (3072x2048)
  u16*   Wob  = (u16*)(w + (20u << 20));     // 8 MB  Wo bf16
  float* qkv  = (float*)(w + (28u << 20));   // 24 MB qkv fp32 (2048x3072)
  u16*   qb   = (u16*)(w + (52u << 20));     // 8 MB  q bf16 roped+scaled
  u16*   kb   = (u16*)(w + (60u << 20));     // 2 MB  k bf16 roped
  u16*   vT   = (u16*)(w + (62u << 20));     // 2 MB  v^T bf16 (512x2048)
  u16*   attn = (u16*)(w + (64u << 20));     // 8 MB  attention out bf16
  (void)ws_size; (void)in_sizes; (void)n_in; (void)out_size;

  cast_bf16_kernel<<<4096, 256, 0, stream>>>(x,  xb);
  cast_bf16_kernel<<<4096, 256, 0, stream>>>(Wq, Wcat);
  cast_bf16_kernel<<<1024, 256, 0, stream>>>(Wk, Wcat + (size_t)E_DIM * E_DIM);
  cast_bf16_kernel<<<1024, 256, 0, stream>>>(Wv, Wcat + (size_t)(E_DIM + KVD) * E_DIM);
  cast_bf16_kernel<<<4096, 256, 0, stream>>>(Wo, Wob);

  gemm_bt_kernel<false><<<dim3(NQKV/128, S_LEN/128), 256, 0, stream>>>(
      xb, Wcat, qkv, nullptr, S_LEN, NQKV, E_DIM);

  rope_split_kernel<<<(S_LEN * 1280) / 256, 256, 0, stream>>>(qkv, qb, kb);
  transpose_v_kernel<<<dim3(S_LEN/32, KVD/32), dim3(32, 8), 0, stream>>>(qkv, vT);

  attn_kernel<<<dim3(16, QH), 256, 0, stream>>>(qb, kb, vT, attn);

  gemm_bt_kernel<true><<<dim3(E_DIM/128, S_LEN/128), 256, 0, stream>>>(
      attn, Wob, out, bo, S_LEN, E_DIM, E_DIM);
}

// Round 3
// 176.371 us; speedup vs baseline: 1.5417x; 1.0759x over previous
//
#include <hip/hip_runtime.h>
#include <stdint.h>

typedef unsigned short u16;
typedef float  f32x4  __attribute__((ext_vector_type(4)));
typedef __bf16 bf16x8 __attribute__((ext_vector_type(8)));
typedef unsigned short u16x8 __attribute__((ext_vector_type(8)));
typedef unsigned short u16x4v __attribute__((ext_vector_type(4)));

#define S_LEN 2048
#define E_DIM 2048
#define HD    128
#define QH    16
#define KVH   4
#define KVD   512
#define NQKV  3072
#define QK_SCALE 0.08838834764831845f  // 1/sqrt(128)

#define AS1 __attribute__((address_space(1)))
#define AS3 __attribute__((address_space(3)))

__device__ __forceinline__ u16 f2bf(float f) {
  union { float f; uint32_t u; } v; v.f = f;
  return (u16)((v.u + 0x7FFFu + ((v.u >> 16) & 1u)) >> 16);
}

// ---------------- cast fp32 -> bf16, 4 elems/thread ----------------
__global__ void cast_bf16_kernel(const float* __restrict__ in, u16* __restrict__ out) {
  int i = blockIdx.x * blockDim.x + threadIdx.x;
  float4 f = reinterpret_cast<const float4*>(in)[i];
  u16x4v o;
  o[0] = f2bf(f.x); o[1] = f2bf(f.y); o[2] = f2bf(f.z); o[3] = f2bf(f.w);
  reinterpret_cast<u16x4v*>(out)[i] = o;
}

// ---------------- GEMM: C[M,N] = A[M,K] * B[N,K]^T (+bias), bf16 in, fp32 out
// 128x128 tile, BK=64, 256 threads (4 waves as 2x2 of 64x64).
// 2-phase pipeline: double-buffered LDS, global_load_lds width-16 issued for
// tile t+1 BEFORE computing tile t, ONE barrier per K-step (vmcnt drains after
// the MFMAs, not before). Source-side XOR swizzle -> conflict-free b128 reads.
template<bool BIAS>
__global__ __launch_bounds__(256) void gemm_bt_kernel(
    const u16* __restrict__ A, const u16* __restrict__ B,
    float* __restrict__ C, const float* __restrict__ bias,
    int M, int N, int K)
{
  __shared__ u16 As[2][128 * 64];
  __shared__ u16 Bs[2][128 * 64];

  const int tid  = threadIdx.x;
  const int lane = tid & 63;
  const int wid  = tid >> 6;
  const int wr   = (wid >> 1) * 64;
  const int wc   = (wid & 1) * 64;
  const int lr   = lane & 15;
  const int kg   = lane >> 4;

  const int bm = blockIdx.y * 128;
  const int bn = blockIdx.x * 128;

  f32x4 acc[4][4];
  #pragma unroll
  for (int r = 0; r < 4; ++r)
    #pragma unroll
    for (int c = 0; c < 4; ++c) acc[r][c] = (f32x4){0.f, 0.f, 0.f, 0.f};

  // staging geometry: wave w covers rows [w*32, w*32+32); lane l covers
  // row w*32 + i*8 + (l>>3), LDS slot (l&7); source chunk = slot ^ (row&7).
  const int l8 = lane & 7;
  const int l3 = lane >> 3;
  const int schunk = l8 ^ l3;  // swizzled source chunk (16B units)

  const u16* gA = A + (size_t)(bm + wid*32 + l3) * K + schunk * 8;
  const u16* gB = B + (size_t)(bn + wid*32 + l3) * K + schunk * 8;

  const int sw = lr & 7;

  auto stage = [&](int buf, int kt) {
    #pragma unroll
    for (int i = 0; i < 4; ++i) {
      __builtin_amdgcn_global_load_lds(
          (const AS1 void*)(gA + (size_t)i * 8 * K + kt),
          (AS3 void*)(&As[buf][wid*32*64 + i*8*64]), 16, 0, 0);
      __builtin_amdgcn_global_load_lds(
          (const AS1 void*)(gB + (size_t)i * 8 * K + kt),
          (AS3 void*)(&Bs[buf][wid*32*64 + i*8*64]), 16, 0, 0);
    }
  };

  stage(0, 0);
  __syncthreads();  // drain prologue loads

  int cur = 0;
  for (int kt = 0; kt < K; kt += 64) {
    if (kt + 64 < K) stage(cur ^ 1, kt + 64);  // in flight across the MFMAs
    #pragma unroll
    for (int kk = 0; kk < 2; ++kk) {
      bf16x8 af[4], bfr[4];
      #pragma unroll
      for (int r = 0; r < 4; ++r)
        af[r] = *reinterpret_cast<const bf16x8*>(
            &As[cur][(wr + r*16 + lr)*64 + ((kk*4 + kg) ^ sw)*8]);
      #pragma unroll
      for (int c = 0; c < 4; ++c)
        bfr[c] = *reinterpret_cast<const bf16x8*>(
            &Bs[cur][(wc + c*16 + lr)*64 + ((kk*4 + kg) ^ sw)*8]);
      #pragma unroll
      for (int r = 0; r < 4; ++r)
        #pragma unroll
        for (int c = 0; c < 4; ++c)
          acc[r][c] = __builtin_amdgcn_mfma_f32_16x16x32_bf16(af[r], bfr[c], acc[r][c], 0, 0, 0);
    }
    __syncthreads();  // single barrier: drains vmcnt after compute, guards reuse
    cur ^= 1;
  }

  const int crow = kg * 4;
  #pragma unroll
  for (int r = 0; r < 4; ++r) {
    #pragma unroll
    for (int c = 0; c < 4; ++c) {
      int gr = bm + wr + r*16 + crow;
      int gc = bn + wc + c*16 + lr;
      float badd = BIAS ? bias[gc] : 0.0f;
      #pragma unroll
      for (int reg = 0; reg < 4; ++reg)
        C[(size_t)(gr + reg)*N + gc] = acc[r][c][reg] + badd;
    }
  }
}

// ---------------- RoPE + split qkv_f32 -> q_bf16 (scaled), k_bf16 ----------------
__global__ void rope_split_kernel(const float* __restrict__ qkv,
                                  u16* __restrict__ qb, u16* __restrict__ kb) {
  int idx = blockIdx.x * blockDim.x + threadIdx.x;  // 0 .. 2048*1280
  int s  = idx / 1280;
  int cp = idx - s * 1280;
  int col = cp * 2;  // q: 0..2047, k: 2048..2559
  const float* src = qkv + (size_t)s * NQKV + col;
  float x0 = src[0], x1 = src[1];
  int p = (col & 127) >> 1;  // pair index within head (0..63)
  float inv = exp2f((float)p * (-13.287712379549449f / 64.0f));  // 10000^(-p/64)
  float ang = (float)s * inv;
  float sn, cs;
  sincosf(ang, &sn, &cs);
  float o0 = x0 * cs - x1 * sn;
  float o1 = x0 * sn + x1 * cs;
  if (col < E_DIM) {
    o0 *= QK_SCALE; o1 *= QK_SCALE;
    qb[(size_t)s * E_DIM + col]     = f2bf(o0);
    qb[(size_t)s * E_DIM + col + 1] = f2bf(o1);
  } else {
    kb[(size_t)s * KVD + (col - E_DIM)]     = f2bf(o0);
    kb[(size_t)s * KVD + (col - E_DIM) + 1] = f2bf(o1);
  }
}

// ---------------- V transpose: qkv_f32 v-block (S x 512) -> vT bf16 (512 x S) ----
__global__ void transpose_v_kernel(const float* __restrict__ qkv, u16* __restrict__ vT) {
  __shared__ float tile[32][33];
  const int sbase = blockIdx.x * 32;
  const int cbase = blockIdx.y * 32;
  const int tx = threadIdx.x;
  const int ty = threadIdx.y;
  #pragma unroll
  for (int i = 0; i < 32; i += 8)
    tile[ty + i][tx] = qkv[(size_t)(sbase + ty + i) * NQKV + (E_DIM + KVD) + cbase + tx];
  __syncthreads();
  #pragma unroll
  for (int i = 0; i < 32; i += 8)
    vT[(size_t)(cbase + ty + i) * S_LEN + sbase + tx] = f2bf(tile[tx][ty + i]);
}

// ---------------- Flash attention tile (per wave: 16 q rows vs 64 kv) ----------
__device__ __forceinline__ void attn_tile(
    int t, int qt, int wid, int lr, int kg,
    const bf16x8* qf, f32x4* o, float* mr, float* ls,
    const u16* ks, const u16* vts, u16* ps)
{
  const int sw = lr & 7;
  f32x4 sacc[4];
  #pragma unroll
  for (int c = 0; c < 4; ++c) sacc[c] = (f32x4){0.f, 0.f, 0.f, 0.f};
  #pragma unroll
  for (int kk = 0; kk < 4; ++kk) {
    #pragma unroll
    for (int c = 0; c < 4; ++c) {
      bf16x8 bfr = *reinterpret_cast<const bf16x8*>(
          &ks[(c*16 + lr)*128 + ((kk*4 + kg) ^ sw)*8]);
      sacc[c] = __builtin_amdgcn_mfma_f32_16x16x32_bf16(qf[kk], bfr, sacc[c], 0, 0, 0);
    }
  }
  if (t == qt) {  // causal mask, diagonal tile only
    #pragma unroll
    for (int c = 0; c < 4; ++c) {
      int rel = (c*16 + lr) - (wid*16 + kg*4);
      #pragma unroll
      for (int reg = 0; reg < 4; ++reg)
        if (rel > reg) sacc[c][reg] = -1e30f;
    }
  }
  float p[4][4];
  #pragma unroll
  for (int reg = 0; reg < 4; ++reg) {
    float mx = fmaxf(fmaxf(sacc[0][reg], sacc[1][reg]), fmaxf(sacc[2][reg], sacc[3][reg]));
    mx = fmaxf(mx, __shfl_xor(mx, 1));
    mx = fmaxf(mx, __shfl_xor(mx, 2));
    mx = fmaxf(mx, __shfl_xor(mx, 4));
    mx = fmaxf(mx, __shfl_xor(mx, 8));
    float nm = fmaxf(mr[reg], mx);
    float sum = 0.f;
    #pragma unroll
    for (int c = 0; c < 4; ++c) {
      p[c][reg] = __expf(sacc[c][reg] - nm);
      sum += p[c][reg];
    }
    sum += __shfl_xor(sum, 1);
    sum += __shfl_xor(sum, 2);
    sum += __shfl_xor(sum, 4);
    sum += __shfl_xor(sum, 8);
    float alpha = __expf(mr[reg] - nm);
    ls[reg] = ls[reg] * alpha + sum;
    mr[reg] = nm;
    #pragma unroll
    for (int d = 0; d < 8; ++d) o[d][reg] *= alpha;
  }
  #pragma unroll
  for (int c = 0; c < 4; ++c)
    #pragma unroll
    for (int reg = 0; reg < 4; ++reg)
      ps[(kg*4 + reg)*72 + c*16 + lr] = f2bf(p[c][reg]);
  #pragma unroll
  for (int kk = 0; kk < 2; ++kk) {
    bf16x8 pa = *reinterpret_cast<const bf16x8*>(&ps[lr*72 + kk*32 + kg*8]);
    #pragma unroll
    for (int d = 0; d < 8; ++d) {
      bf16x8 vb = *reinterpret_cast<const bf16x8*>(
          &vts[(d*16 + lr)*64 + ((kk*4 + kg) ^ sw)*8]);
      o[d] = __builtin_amdgcn_mfma_f32_16x16x32_bf16(pa, vb, o[d], 0, 0, 0);
    }
  }
}

// ---------------- Flash attention (causal, GQA 4:1) ----------------------------
// 512 blocks, one 64-row q-tile each -> 2 blocks/CU (73 KB LDS), 8 waves/CU.
// CU-level balance: block b (b<256) takes qt=b&31; block b+256 takes 31-(b&31);
// round-robin dispatch co-locates them, each CU pair sums to 33 kv-iterations.
// K/V double-buffered (XOR-swizzled), async-stage split, 1 barrier/tile.
__global__ __launch_bounds__(256, 2) void attn_kernel(
    const u16* __restrict__ Q, const u16* __restrict__ Kc,
    const u16* __restrict__ VT, u16* __restrict__ Out)
{
  __shared__ u16 Ks[2][64 * 128];
  __shared__ u16 VTs[2][128 * 64];
  __shared__ u16 Ps[4][16 * 72];

  const int x = blockIdx.x;
  int qt, h;
  if (x < 256) { qt = x & 31; h = x >> 5; }
  else         { int xp = x - 256; qt = 31 - (xp & 31); h = 8 + (xp >> 5); }
  const int kvh = h >> 2;
  const int tid  = threadIdx.x;
  const int lane = tid & 63;
  const int wid  = tid >> 6;
  const int lr   = lane & 15;
  const int kg   = lane >> 4;

  const int NT = qt + 1;

  bf16x8 qf[4];
  {
    const u16* qa = Q + (size_t)(qt*64 + wid*16 + lr) * E_DIM + h * HD + kg * 8;
    #pragma unroll
    for (int kk = 0; kk < 4; ++kk)
      qf[kk] = *reinterpret_cast<const bf16x8*>(qa + kk * 32);
  }

  f32x4 o[8];
  float mr[4], ls[4];
  #pragma unroll
  for (int d = 0; d < 8; ++d) o[d] = (f32x4){0.f,0.f,0.f,0.f};
  #pragma unroll
  for (int r = 0; r < 4; ++r) { mr[r] = -1e30f; ls[r] = 0.f; }

  u16x8 kreg[4], vreg[4];
  const u16* kbase = Kc + kvh * HD;
  const u16* vbase = VT + (size_t)(kvh * HD) * S_LEN;

  auto stage_load = [&](int t) {
    #pragma unroll
    for (int i = 0; i < 4; ++i) {
      int c = i * 256 + tid;
      kreg[i] = *reinterpret_cast<const u16x8*>(
          kbase + (size_t)(t*64 + (c >> 4)) * KVD + (c & 15) * 8);
      vreg[i] = *reinterpret_cast<const u16x8*>(
          vbase + (size_t)(c >> 3) * S_LEN + t*64 + (c & 7) * 8);
    }
  };
  auto stage_write = [&](int b) {
    #pragma unroll
    for (int i = 0; i < 4; ++i) {
      int c = i * 256 + tid;
      int kr = c >> 4, kc = c & 15;
      *reinterpret_cast<u16x8*>(&Ks[b][kr*128 + (kc ^ (kr & 7))*8]) = kreg[i];
      int vr = c >> 3, vc = c & 7;
      *reinterpret_cast<u16x8*>(&VTs[b][vr*64 + (vc ^ (vr & 7))*8]) = vreg[i];
    }
  };

  int p = 0;
  stage_load(0);
  stage_write(0);
  __syncthreads();

  for (int t = 0; t < NT; ++t) {
    if (t + 1 < NT) stage_load(t + 1);  // issue early: latency hides under MFMAs
    attn_tile(t, qt, wid, lr, kg, qf, o, mr, ls, Ks[p], VTs[p], Ps[wid]);
    if (t + 1 < NT) {
      stage_write(p ^ 1);  // vmcnt wait lands here, after compute
      __syncthreads();     // single barrier per tile
      p ^= 1;
    }
  }

  #pragma unroll
  for (int reg = 0; reg < 4; ++reg) {
    float inv = 1.0f / ls[reg];
    int grow = qt*64 + wid*16 + kg*4 + reg;
    #pragma unroll
    for (int d = 0; d < 8; ++d)
      Out[(size_t)grow * E_DIM + h * HD + d*16 + lr] = f2bf(o[d][reg] * inv);
  }
}

// ---------------- launch ----------------
extern "C" void kernel_launch(void* const* d_in, const int* in_sizes, int n_in,
                              void* d_out, int out_size, void* d_ws, size_t ws_size,
                              hipStream_t stream)
{
  const float* x  = (const float*)d_in[0];
  const float* Wq = (const float*)d_in[1];
  const float* Wk = (const float*)d_in[2];
  const float* Wv = (const float*)d_in[3];
  const float* Wo = (const float*)d_in[4];
  const float* bo = (const float*)d_in[5];
  float* out = (float*)d_out;

  char* w = (char*)d_ws;
  u16*   xb   = (u16*)(w);                   // 8 MB  x bf16 (2048x2048)
  u16*   Wcat = (u16*)(w + (8u  << 20));     // 12 MB [Wq;Wk;Wv] bf16 (3072x2048)
  u16*   Wob  = (u16*)(w + (20u << 20));     // 8 MB  Wo bf16
  float* qkv  = (float*)(w + (28u << 20));   // 24 MB qkv fp32 (2048x3072)
  u16*   qb   = (u16*)(w + (52u << 20));     // 8 MB  q bf16 roped+scaled
  u16*   kb   = (u16*)(w + (60u << 20));     // 2 MB  k bf16 roped
  u16*   vT   = (u16*)(w + (62u << 20));     // 2 MB  v^T bf16 (512x2048)
  u16*   attn = (u16*)(w + (64u << 20));     // 8 MB  attention out bf16
  (void)ws_size; (void)in_sizes; (void)n_in; (void)out_size;

  cast_bf16_kernel<<<4096, 256, 0, stream>>>(x,  xb);
  cast_bf16_kernel<<<4096, 256, 0, stream>>>(Wq, Wcat);
  cast_bf16_kernel<<<1024, 256, 0, stream>>>(Wk, Wcat + (size_t)E_DIM * E_DIM);
  cast_bf16_kernel<<<1024, 256, 0, stream>>>(Wv, Wcat + (size_t)(E_DIM + KVD) * E_DIM);
  cast_bf16_kernel<<<4096, 256, 0, stream>>>(Wo, Wob);

  gemm_bt_kernel<false><<<dim3(NQKV/128, S_LEN/128), 256, 0, stream>>>(
      xb, Wcat, qkv, nullptr, S_LEN, NQKV, E_DIM);

  rope_split_kernel<<<(S_LEN * 1280) / 256, 256, 0, stream>>>(qkv, qb, kb);
  transpose_v_kernel<<<dim3(S_LEN/32, KVD/32), dim3(32, 8), 0, stream>>>(qkv, vT);

  attn_kernel<<<512, 256, 0, stream>>>(qb, kb, vT, attn);

  gemm_bt_kernel<true><<<dim3(E_DIM/128, S_LEN/128), 256, 0, stream>>>(
      attn, Wob, out, bo, S_LEN, E_DIM, E_DIM);
}

// Round 4
// 153.595 us; speedup vs baseline: 1.7703x; 1.1483x over previous
//
#include <hip/hip_runtime.h>
#include <stdint.h>

typedef unsigned short u16;
typedef float  f32x4  __attribute__((ext_vector_type(4)));
typedef __bf16 bf16x8 __attribute__((ext_vector_type(8)));
typedef __bf16 bf16x4 __attribute__((ext_vector_type(4)));
typedef unsigned short u16x8 __attribute__((ext_vector_type(8)));
typedef unsigned short u16x4v __attribute__((ext_vector_type(4)));

#define S_LEN 2048
#define E_DIM 2048
#define HD    128
#define QH    16
#define KVH   4
#define KVD   512
#define NQKV  3072
#define QK_SCALE 0.08838834764831845f  // 1/sqrt(128)

#define AS1 __attribute__((address_space(1)))
#define AS3 __attribute__((address_space(3)))

__device__ __forceinline__ u16 f2bf(float f) {
  union { float f; uint32_t u; } v; v.f = f;
  return (u16)((v.u + 0x7FFFu + ((v.u >> 16) & 1u)) >> 16);
}

// ---------------- cast fp32 -> bf16, 4 elems/thread ----------------
__global__ void cast_bf16_kernel(const float* __restrict__ in, u16* __restrict__ out) {
  int i = blockIdx.x * blockDim.x + threadIdx.x;
  float4 f = reinterpret_cast<const float4*>(in)[i];
  u16x4v o;
  o[0] = f2bf(f.x); o[1] = f2bf(f.y); o[2] = f2bf(f.z); o[3] = f2bf(f.w);
  reinterpret_cast<u16x4v*>(out)[i] = o;
}

// ---------------- GEMM: C[M,N] = A[M,K] * B[N,K]^T (+bias), bf16 in, fp32 out
// 128x128 tile, BK=64, 256 threads (4 waves as 2x2 of 64x64).
// 2-phase pipeline: double-buffered LDS, global_load_lds width-16 issued for
// tile t+1 BEFORE computing tile t, ONE barrier per K-step. Source-side XOR
// swizzle -> conflict-free b128 reads.
template<bool BIAS>
__global__ __launch_bounds__(256) void gemm_bt_kernel(
    const u16* __restrict__ A, const u16* __restrict__ B,
    float* __restrict__ C, const float* __restrict__ bias,
    int M, int N, int K)
{
  __shared__ u16 As[2][128 * 64];
  __shared__ u16 Bs[2][128 * 64];

  const int tid  = threadIdx.x;
  const int lane = tid & 63;
  const int wid  = tid >> 6;
  const int wr   = (wid >> 1) * 64;
  const int wc   = (wid & 1) * 64;
  const int lr   = lane & 15;
  const int kg   = lane >> 4;

  const int bm = blockIdx.y * 128;
  const int bn = blockIdx.x * 128;

  f32x4 acc[4][4];
  #pragma unroll
  for (int r = 0; r < 4; ++r)
    #pragma unroll
    for (int c = 0; c < 4; ++c) acc[r][c] = (f32x4){0.f, 0.f, 0.f, 0.f};

  const int l8 = lane & 7;
  const int l3 = lane >> 3;
  const int schunk = l8 ^ l3;  // swizzled source chunk (16B units)

  const u16* gA = A + (size_t)(bm + wid*32 + l3) * K + schunk * 8;
  const u16* gB = B + (size_t)(bn + wid*32 + l3) * K + schunk * 8;

  const int sw = lr & 7;

  auto stage = [&](int buf, int kt) {
    #pragma unroll
    for (int i = 0; i < 4; ++i) {
      __builtin_amdgcn_global_load_lds(
          (const AS1 void*)(gA + (size_t)i * 8 * K + kt),
          (AS3 void*)(&As[buf][wid*32*64 + i*8*64]), 16, 0, 0);
      __builtin_amdgcn_global_load_lds(
          (const AS1 void*)(gB + (size_t)i * 8 * K + kt),
          (AS3 void*)(&Bs[buf][wid*32*64 + i*8*64]), 16, 0, 0);
    }
  };

  stage(0, 0);
  __syncthreads();  // drain prologue loads

  int cur = 0;
  for (int kt = 0; kt < K; kt += 64) {
    if (kt + 64 < K) stage(cur ^ 1, kt + 64);  // in flight across the MFMAs
    #pragma unroll
    for (int kk = 0; kk < 2; ++kk) {
      bf16x8 af[4], bfr[4];
      #pragma unroll
      for (int r = 0; r < 4; ++r)
        af[r] = *reinterpret_cast<const bf16x8*>(
            &As[cur][(wr + r*16 + lr)*64 + ((kk*4 + kg) ^ sw)*8]);
      #pragma unroll
      for (int c = 0; c < 4; ++c)
        bfr[c] = *reinterpret_cast<const bf16x8*>(
            &Bs[cur][(wc + c*16 + lr)*64 + ((kk*4 + kg) ^ sw)*8]);
      #pragma unroll
      for (int r = 0; r < 4; ++r)
        #pragma unroll
        for (int c = 0; c < 4; ++c)
          acc[r][c] = __builtin_amdgcn_mfma_f32_16x16x32_bf16(af[r], bfr[c], acc[r][c], 0, 0, 0);
    }
    __syncthreads();  // single barrier: drains vmcnt after compute, guards reuse
    cur ^= 1;
  }

  const int crow = kg * 4;
  #pragma unroll
  for (int r = 0; r < 4; ++r) {
    #pragma unroll
    for (int c = 0; c < 4; ++c) {
      int gr = bm + wr + r*16 + crow;
      int gc = bn + wc + c*16 + lr;
      float badd = BIAS ? bias[gc] : 0.0f;
      #pragma unroll
      for (int reg = 0; reg < 4; ++reg)
        C[(size_t)(gr + reg)*N + gc] = acc[r][c][reg] + badd;
    }
  }
}

// ---------------- RoPE + split qkv_f32 -> q_bf16 (scaled), k_bf16 ----------------
__global__ void rope_split_kernel(const float* __restrict__ qkv,
                                  u16* __restrict__ qb, u16* __restrict__ kb) {
  int idx = blockIdx.x * blockDim.x + threadIdx.x;  // 0 .. 2048*1280
  int s  = idx / 1280;
  int cp = idx - s * 1280;
  int col = cp * 2;  // q: 0..2047, k: 2048..2559
  const float* src = qkv + (size_t)s * NQKV + col;
  float x0 = src[0], x1 = src[1];
  int p = (col & 127) >> 1;  // pair index within head (0..63)
  float inv = exp2f((float)p * (-13.287712379549449f / 64.0f));  // 10000^(-p/64)
  float ang = (float)s * inv;
  float sn, cs;
  sincosf(ang, &sn, &cs);
  float o0 = x0 * cs - x1 * sn;
  float o1 = x0 * sn + x1 * cs;
  if (col < E_DIM) {
    o0 *= QK_SCALE; o1 *= QK_SCALE;
    qb[(size_t)s * E_DIM + col]     = f2bf(o0);
    qb[(size_t)s * E_DIM + col + 1] = f2bf(o1);
  } else {
    kb[(size_t)s * KVD + (col - E_DIM)]     = f2bf(o0);
    kb[(size_t)s * KVD + (col - E_DIM) + 1] = f2bf(o1);
  }
}

// ---------------- V transpose: qkv_f32 v-block (S x 512) -> vT bf16 (512 x S) ----
__global__ void transpose_v_kernel(const float* __restrict__ qkv, u16* __restrict__ vT) {
  __shared__ float tile[32][33];
  const int sbase = blockIdx.x * 32;
  const int cbase = blockIdx.y * 32;
  const int tx = threadIdx.x;
  const int ty = threadIdx.y;
  #pragma unroll
  for (int i = 0; i < 32; i += 8)
    tile[ty + i][tx] = qkv[(size_t)(sbase + ty + i) * NQKV + (E_DIM + KVD) + cbase + tx];
  __syncthreads();
  #pragma unroll
  for (int i = 0; i < 32; i += 8)
    vT[(size_t)(cbase + ty + i) * S_LEN + sbase + tx] = f2bf(tile[tx][ty + i]);
}

// ---------------- Flash attention tile, SWAPPED QK^T -------------------------
// S^T = mfma(K_frag, Q_frag): lane (lr,kg) holds S[kv=c*16+kg*4+reg][q=lr].
// Softmax per lane: in-register 16-val trees + 2 shfl_xor (kg groups).
// Defer-max (THR=8): rescale branch is wave-uniform, fires ~once per q-tile.
__device__ __forceinline__ void attn_tile(
    int t, int qt, int wid, int lr, int kg,
    const bf16x8* qf, f32x4* o, float& mr, float& ls,
    const u16* ks, const u16* vts, u16* ps)
{
  const int sw = lr & 7;
  f32x4 st[4];
  #pragma unroll
  for (int c = 0; c < 4; ++c) st[c] = (f32x4){0.f, 0.f, 0.f, 0.f};
  __builtin_amdgcn_s_setprio(1);
  #pragma unroll
  for (int kk = 0; kk < 4; ++kk) {
    #pragma unroll
    for (int c = 0; c < 4; ++c) {
      bf16x8 kfr = *reinterpret_cast<const bf16x8*>(
          &ks[(c*16 + lr)*128 + ((kk*4 + kg) ^ sw)*8]);
      st[c] = __builtin_amdgcn_mfma_f32_16x16x32_bf16(kfr, qf[kk], st[c], 0, 0, 0);
    }
  }
  __builtin_amdgcn_s_setprio(0);
  if (t == qt) {  // causal: mask kv > q (local coords)
    #pragma unroll
    for (int c = 0; c < 4; ++c)
      #pragma unroll
      for (int reg = 0; reg < 4; ++reg)
        if (c*16 + kg*4 + reg > wid*16 + lr) st[c][reg] = -1e30f;
  }
  // row max for q=lr: in-register tree + 2 cross-kg shfl
  float cm[4];
  #pragma unroll
  for (int c = 0; c < 4; ++c)
    cm[c] = fmaxf(fmaxf(st[c][0], st[c][1]), fmaxf(st[c][2], st[c][3]));
  float pm = fmaxf(fmaxf(cm[0], cm[1]), fmaxf(cm[2], cm[3]));
  pm = fmaxf(pm, __shfl_xor(pm, 16));
  pm = fmaxf(pm, __shfl_xor(pm, 32));

  if (!__all(pm - mr <= 8.0f)) {  // defer-max: rare after first tile
    float nm = fmaxf(mr, pm);
    float alpha = __expf(mr - nm);
    ls *= alpha;
    mr = nm;
    float ar[4];
    #pragma unroll
    for (int reg = 0; reg < 4; ++reg)
      ar[reg] = __shfl(alpha, kg*4 + reg);  // alpha of q = kg*4+reg
    #pragma unroll
    for (int d = 0; d < 8; ++d)
      #pragma unroll
      for (int reg = 0; reg < 4; ++reg)
        o[d][reg] *= ar[reg];
  }

  float p[4][4];
  float csum[4];
  #pragma unroll
  for (int c = 0; c < 4; ++c) {
    #pragma unroll
    for (int reg = 0; reg < 4; ++reg)
      p[c][reg] = __expf(st[c][reg] - mr);
    csum[c] = (p[c][0] + p[c][1]) + (p[c][2] + p[c][3]);
  }
  float sum = (csum[0] + csum[1]) + (csum[2] + csum[3]);
  sum += __shfl_xor(sum, 16);
  sum += __shfl_xor(sum, 32);
  ls += sum;

  // pack P -> Ps[q=lr][kv], 4 bf16 per ds_write_b64 (reg-contiguous kv)
  #pragma unroll
  for (int c = 0; c < 4; ++c) {
    bf16x4 pk;
    #pragma unroll
    for (int reg = 0; reg < 4; ++reg) pk[reg] = (__bf16)p[c][reg];
    *reinterpret_cast<bf16x4*>(&ps[lr*72 + c*16 + kg*4]) = pk;
  }
  // O += P * V
  __builtin_amdgcn_s_setprio(1);
  #pragma unroll
  for (int kk = 0; kk < 2; ++kk) {
    bf16x8 pa = *reinterpret_cast<const bf16x8*>(&ps[lr*72 + kk*32 + kg*8]);
    #pragma unroll
    for (int d = 0; d < 8; ++d) {
      bf16x8 vb = *reinterpret_cast<const bf16x8*>(
          &vts[(d*16 + lr)*64 + ((kk*4 + kg) ^ sw)*8]);
      o[d] = __builtin_amdgcn_mfma_f32_16x16x32_bf16(pa, vb, o[d], 0, 0, 0);
    }
  }
  __builtin_amdgcn_s_setprio(0);
}

// ---------------- Flash attention (causal, GQA 4:1) ----------------------------
// 512 blocks, one 64-row q-tile each -> 2 blocks/CU (73 KB LDS).
// CU-level balance: block b (b<256) takes qt=b&31; block b+256 takes 31-(b&31).
// K/V double-buffered (XOR-swizzled), async-stage split, 1 barrier/tile.
__global__ __launch_bounds__(256, 2) void attn_kernel(
    const u16* __restrict__ Q, const u16* __restrict__ Kc,
    const u16* __restrict__ VT, u16* __restrict__ Out)
{
  __shared__ u16 Ks[2][64 * 128];
  __shared__ u16 VTs[2][128 * 64];
  __shared__ u16 Ps[4][16 * 72];

  const int x = blockIdx.x;
  int qt, h;
  if (x < 256) { qt = x & 31; h = x >> 5; }
  else         { int xp = x - 256; qt = 31 - (xp & 31); h = 8 + (xp >> 5); }
  const int kvh = h >> 2;
  const int tid  = threadIdx.x;
  const int lane = tid & 63;
  const int wid  = tid >> 6;
  const int lr   = lane & 15;
  const int kg   = lane >> 4;

  const int NT = qt + 1;

  bf16x8 qf[4];
  {
    const u16* qa = Q + (size_t)(qt*64 + wid*16 + lr) * E_DIM + h * HD + kg * 8;
    #pragma unroll
    for (int kk = 0; kk < 4; ++kk)
      qf[kk] = *reinterpret_cast<const bf16x8*>(qa + kk * 32);
  }

  f32x4 o[8];
  #pragma unroll
  for (int d = 0; d < 8; ++d) o[d] = (f32x4){0.f,0.f,0.f,0.f};
  float mr = -1e30f, ls = 0.f;

  u16x8 kreg[4], vreg[4];
  const u16* kbase = Kc + kvh * HD;
  const u16* vbase = VT + (size_t)(kvh * HD) * S_LEN;

  auto stage_load = [&](int t) {
    #pragma unroll
    for (int i = 0; i < 4; ++i) {
      int c = i * 256 + tid;
      kreg[i] = *reinterpret_cast<const u16x8*>(
          kbase + (size_t)(t*64 + (c >> 4)) * KVD + (c & 15) * 8);
      vreg[i] = *reinterpret_cast<const u16x8*>(
          vbase + (size_t)(c >> 3) * S_LEN + t*64 + (c & 7) * 8);
    }
  };
  auto stage_write = [&](int b) {
    #pragma unroll
    for (int i = 0; i < 4; ++i) {
      int c = i * 256 + tid;
      int kr = c >> 4, kc = c & 15;
      *reinterpret_cast<u16x8*>(&Ks[b][kr*128 + (kc ^ (kr & 7))*8]) = kreg[i];
      int vr = c >> 3, vc = c & 7;
      *reinterpret_cast<u16x8*>(&VTs[b][vr*64 + (vc ^ (vr & 7))*8]) = vreg[i];
    }
  };

  int p = 0;
  stage_load(0);
  stage_write(0);
  __syncthreads();

  for (int t = 0; t < NT; ++t) {
    if (t + 1 < NT) stage_load(t + 1);  // issue early: latency hides under MFMAs
    attn_tile(t, qt, wid, lr, kg, qf, o, mr, ls, Ks[p], VTs[p], Ps[wid]);
    if (t + 1 < NT) {
      stage_write(p ^ 1);  // vmcnt wait lands here, after compute
      __syncthreads();     // single barrier per tile
      p ^= 1;
    }
  }

  {
    float inv = 1.0f / ls;  // for q = lr
    float ivq[4];
    #pragma unroll
    for (int reg = 0; reg < 4; ++reg)
      ivq[reg] = __shfl(inv, kg*4 + reg);
    #pragma unroll
    for (int reg = 0; reg < 4; ++reg) {
      int grow = qt*64 + wid*16 + kg*4 + reg;
      #pragma unroll
      for (int d = 0; d < 8; ++d)
        Out[(size_t)grow * E_DIM + h * HD + d*16 + lr] =
            __builtin_bit_cast(u16, (__bf16)(o[d][reg] * ivq[reg]));
    }
  }
}

// ---------------- launch ----------------
extern "C" void kernel_launch(void* const* d_in, const int* in_sizes, int n_in,
                              void* d_out, int out_size, void* d_ws, size_t ws_size,
                              hipStream_t stream)
{
  const float* x  = (const float*)d_in[0];
  const float* Wq = (const float*)d_in[1];
  const float* Wk = (const float*)d_in[2];
  const float* Wv = (const float*)d_in[3];
  const float* Wo = (const float*)d_in[4];
  const float* bo = (const float*)d_in[5];
  float* out = (float*)d_out;

  char* w = (char*)d_ws;
  u16*   xb   = (u16*)(w);                   // 8 MB  x bf16 (2048x2048)
  u16*   Wcat = (u16*)(w + (8u  << 20));     // 12 MB [Wq;Wk;Wv] bf16 (3072x2048)
  u16*   Wob  = (u16*)(w + (20u << 20));     // 8 MB  Wo bf16
  float* qkv  = (float*)(w + (28u << 20));   // 24 MB qkv fp32 (2048x3072)
  u16*   qb   = (u16*)(w + (52u << 20));     // 8 MB  q bf16 roped+scaled
  u16*   kb   = (u16*)(w + (60u << 20));     // 2 MB  k bf16 roped
  u16*   vT   = (u16*)(w + (62u << 20));     // 2 MB  v^T bf16 (512x2048)
  u16*   attn = (u16*)(w + (64u << 20));     // 8 MB  attention out bf16
  (void)ws_size; (void)in_sizes; (void)n_in; (void)out_size;

  cast_bf16_kernel<<<4096, 256, 0, stream>>>(x,  xb);
  cast_bf16_kernel<<<4096, 256, 0, stream>>>(Wq, Wcat);
  cast_bf16_kernel<<<1024, 256, 0, stream>>>(Wk, Wcat + (size_t)E_DIM * E_DIM);
  cast_bf16_kernel<<<1024, 256, 0, stream>>>(Wv, Wcat + (size_t)(E_DIM + KVD) * E_DIM);
  cast_bf16_kernel<<<4096, 256, 0, stream>>>(Wo, Wob);

  gemm_bt_kernel<false><<<dim3(NQKV/128, S_LEN/128), 256, 0, stream>>>(
      xb, Wcat, qkv, nullptr, S_LEN, NQKV, E_DIM);

  rope_split_kernel<<<(S_LEN * 1280) / 256, 256, 0, stream>>>(qkv, qb, kb);
  transpose_v_kernel<<<dim3(S_LEN/32, KVD/32), dim3(32, 8), 0, stream>>>(qkv, vT);

  attn_kernel<<<512, 256, 0, stream>>>(qb, kb, vT, attn);

  gemm_bt_kernel<true><<<dim3(E_DIM/128, S_LEN/128), 256, 0, stream>>>(
      attn, Wob, out, bo, S_LEN, E_DIM, E_DIM);
}